// Round 1
// baseline (1609.262 us; speedup 1.0000x reference)
//
#include <hip/hip_runtime.h>
#include <math.h>

constexpr int kN   = 50000;
constexpr int kR   = 8;
constexpr int kIn  = 128;
constexpr int kHid = 128;
constexpr int kOut = 40;
constexpr int kNT  = 16;            // dst nodes per block (50000 % 16 == 0 -> no tail)
constexpr float kBnEps = 1e-5f;

// ---------------------------------------------------------------------------
// Layer 1: h1[n][c] = relu(bn( (sum_r agg_r[n] @ W1[r]) / deg ))
// Block: 256 threads, 16 dst nodes. LDS agg[16][8*128] = 64 KB.
// ---------------------------------------------------------------------------
__global__ __launch_bounds__(256, 2)
void rgcn_layer1(const float* __restrict__ x,
                 const float* __restrict__ W1,     // flat [8*128][128]
                 const float* __restrict__ gamma,
                 const float* __restrict__ beta,
                 const float* __restrict__ mean,
                 const float* __restrict__ var,
                 const int*   __restrict__ ptr,
                 const int*   __restrict__ idx,
                 const int*   __restrict__ etype,
                 float*       __restrict__ h1)
{
    __shared__ float agg[kNT][kR * kIn];          // agg[n][r*128 + d]
    const int tid  = threadIdx.x;
    const int base = blockIdx.x * kNT;

    for (int i = tid; i < kNT * kR * kIn; i += 256)
        (&agg[0][0])[i] = 0.0f;
    __syncthreads();

    // ---- Phase A: per-relation neighbor-feature sums -----------------------
    {
        const int d  = tid & (kIn - 1);           // feature dim owned
        const int gg = tid >> 7;                  // 0/1: which node of the pair
        for (int np = 0; np < kNT / 2; ++np) {
            const int n    = np * 2 + gg;
            const int node = base + n;
            const int p0 = ptr[node], p1 = ptr[node + 1];
            float* arow = agg[n];
            for (int e = p0; e < p1; ++e) {
                const int src = idx[e];
                const int r   = etype[e];
                arow[r * kIn + d] += x[src * kIn + d];
            }
        }
    }
    __syncthreads();

    // ---- Phase B: [16 x 1024] @ [1024 x 128] register-tiled ----------------
    const int h2 = tid & 63;                      // channel pair: 2*h2, 2*h2+1
    const int ng = tid >> 6;                      // nodes ng*4 .. ng*4+3
    float acc[4][2];
    #pragma unroll
    for (int j = 0; j < 4; ++j) { acc[j][0] = 0.f; acc[j][1] = 0.f; }

    const int K = kR * kIn;                       // 1024
    for (int k0 = 0; k0 < K; k0 += 4) {
        const float4 a0 = *(const float4*)&agg[ng * 4 + 0][k0];
        const float4 a1 = *(const float4*)&agg[ng * 4 + 1][k0];
        const float4 a2 = *(const float4*)&agg[ng * 4 + 2][k0];
        const float4 a3 = *(const float4*)&agg[ng * 4 + 3][k0];
        #pragma unroll
        for (int j = 0; j < 4; ++j) {
            const float2 w = *(const float2*)&W1[(k0 + j) * kHid + h2 * 2];
            const float b0 = (&a0.x)[j], b1 = (&a1.x)[j];
            const float b2 = (&a2.x)[j], b3 = (&a3.x)[j];
            acc[0][0] += b0 * w.x;  acc[0][1] += b0 * w.y;
            acc[1][0] += b1 * w.x;  acc[1][1] += b1 * w.y;
            acc[2][0] += b2 * w.x;  acc[2][1] += b2 * w.y;
            acc[3][0] += b3 * w.x;  acc[3][1] += b3 * w.y;
        }
    }

    // ---- Epilogue: deg norm + BN (eval) + ReLU -----------------------------
    const int c0 = h2 * 2;
    const float is0 = rsqrtf(var[c0] + kBnEps);
    const float is1 = rsqrtf(var[c0 + 1] + kBnEps);
    const float g0 = gamma[c0] * is0,  g1 = gamma[c0 + 1] * is1;
    const float m0 = mean[c0],         m1 = mean[c0 + 1];
    const float bt0 = beta[c0],        bt1 = beta[c0 + 1];
    #pragma unroll
    for (int j = 0; j < 4; ++j) {
        const int node = base + ng * 4 + j;
        const float invdeg = 1.0f / (float)(ptr[node + 1] - ptr[node]);
        float v0 = (acc[j][0] * invdeg - m0) * g0 + bt0;
        float v1 = (acc[j][1] * invdeg - m1) * g1 + bt1;
        v0 = v0 > 0.f ? v0 : 0.f;
        v1 = v1 > 0.f ? v1 : 0.f;
        h1[node * kHid + c0]     = v0;
        h1[node * kHid + c0 + 1] = v1;
    }
}

// ---------------------------------------------------------------------------
// Layer 2: out[n][o] = log_softmax( (sum_r agg_r[n] @ W2[r]) / deg )
// ---------------------------------------------------------------------------
__global__ __launch_bounds__(256, 2)
void rgcn_layer2(const float* __restrict__ h1,
                 const float* __restrict__ W2,     // flat [8*128][40]
                 const int*   __restrict__ ptr,
                 const int*   __restrict__ idx,
                 const int*   __restrict__ etype,
                 float*       __restrict__ out)
{
    __shared__ float agg[kNT][kR * kHid];         // 64 KB
    const int tid  = threadIdx.x;
    const int base = blockIdx.x * kNT;

    for (int i = tid; i < kNT * kR * kHid; i += 256)
        (&agg[0][0])[i] = 0.0f;
    __syncthreads();

    // ---- Phase A: per-relation sums of h1 ----------------------------------
    {
        const int d  = tid & (kHid - 1);
        const int gg = tid >> 7;
        for (int np = 0; np < kNT / 2; ++np) {
            const int n    = np * 2 + gg;
            const int node = base + n;
            const int p0 = ptr[node], p1 = ptr[node + 1];
            float* arow = agg[n];
            for (int e = p0; e < p1; ++e) {
                const int src = idx[e];
                const int r   = etype[e];
                arow[r * kHid + d] += h1[src * kHid + d];
            }
        }
    }
    __syncthreads();

    // ---- Phase B: [16 x 1024] @ [1024 x 40] --------------------------------
    const int o  = tid & 63;                      // logit channel (active o<40)
    const int ng = tid >> 6;                      // one wave per node group
    float acc[4] = {0.f, 0.f, 0.f, 0.f};

    const int K = kR * kHid;                      // 1024
    if (o < kOut) {
        for (int k0 = 0; k0 < K; k0 += 4) {
            const float4 a0 = *(const float4*)&agg[ng * 4 + 0][k0];
            const float4 a1 = *(const float4*)&agg[ng * 4 + 1][k0];
            const float4 a2 = *(const float4*)&agg[ng * 4 + 2][k0];
            const float4 a3 = *(const float4*)&agg[ng * 4 + 3][k0];
            #pragma unroll
            for (int j = 0; j < 4; ++j) {
                const float w = W2[(k0 + j) * kOut + o];
                acc[0] += (&a0.x)[j] * w;
                acc[1] += (&a1.x)[j] * w;
                acc[2] += (&a2.x)[j] * w;
                acc[3] += (&a3.x)[j] * w;
            }
        }
    }

    // ---- Epilogue: deg norm + log_softmax over 40 logits (wave reduce) -----
    #pragma unroll
    for (int j = 0; j < 4; ++j) {
        const int node = base + ng * 4 + j;
        const float invdeg = 1.0f / (float)(ptr[node + 1] - ptr[node]);
        const float v = (o < kOut) ? acc[j] * invdeg : -INFINITY;
        float m = v;
        #pragma unroll
        for (int off = 32; off > 0; off >>= 1)
            m = fmaxf(m, __shfl_xor(m, off, 64));
        float s = (o < kOut) ? expf(v - m) : 0.f;
        #pragma unroll
        for (int off = 32; off > 0; off >>= 1)
            s += __shfl_xor(s, off, 64);
        if (o < kOut)
            out[node * kOut + o] = v - m - logf(s);
    }
}

// ---------------------------------------------------------------------------
extern "C" void kernel_launch(void* const* d_in, const int* in_sizes, int n_in,
                              void* d_out, int out_size, void* d_ws, size_t ws_size,
                              hipStream_t stream)
{
    const float* x     = (const float*)d_in[0];
    const float* W1    = (const float*)d_in[1];
    const float* W2    = (const float*)d_in[2];
    const float* gamma = (const float*)d_in[3];
    const float* beta  = (const float*)d_in[4];
    const float* mean  = (const float*)d_in[5];
    const float* var   = (const float*)d_in[6];
    const int*   ptr   = (const int*)d_in[7];
    const int*   idx   = (const int*)d_in[8];
    const int*   et    = (const int*)d_in[9];
    float*       out   = (float*)d_out;
    float*       h1    = (float*)d_ws;            // [50000][128] f32 = 25.6 MB

    dim3 grid(kN / kNT), block(256);
    rgcn_layer1<<<grid, block, 0, stream>>>(x, W1, gamma, beta, mean, var,
                                            ptr, idx, et, h1);
    rgcn_layer2<<<grid, block, 0, stream>>>(h1, W2, ptr, idx, et, out);
}

// Round 2
// 1103.046 us; speedup vs baseline: 1.4589x; 1.4589x over previous
//
#include <hip/hip_runtime.h>
#include <math.h>

constexpr int kN   = 50000;
constexpr int kR   = 8;
constexpr int kIn  = 128;
constexpr int kHid = 128;
constexpr int kOut = 40;
constexpr int kNT  = 16;            // dst nodes per block (50000 % 16 == 0)
constexpr float kBnEps = 1e-5f;

// ---------------------------------------------------------------------------
// Phase A (shared by both layers): register-accumulated per-relation sums.
// One wave per dst node; lane owns feature pair d = lane*2, lane*2+1.
// Edge (src, etype) are wave-uniform -> readfirstlane + scalar-branch select
// into 8 float2 register accumulators; no LDS RMW chain.
// ---------------------------------------------------------------------------
template <int K>
__device__ inline void phaseA(const float* __restrict__ feat,
                              const int*   __restrict__ ptr,
                              const int*   __restrict__ idx,
                              const int*   __restrict__ etype,
                              int base, float (*agg)[kR * K])
{
    const int tid  = threadIdx.x;
    const int lane = tid & 63;
    const int wid  = tid >> 6;            // 4 waves
    const int d2   = lane * 2;

    for (int t = 0; t < kNT / 4; ++t) {
        const int n    = t * 4 + wid;
        const int node = base + n;
        const int p0   = ptr[node];
        const int deg  = ptr[node + 1] - p0;

        float2 acc[kR];
        #pragma unroll
        for (int r = 0; r < kR; ++r) acc[r] = make_float2(0.f, 0.f);

        if (deg == 16) {                  // fixed-degree fast path (always hit)
            const int vi = idx[p0 + (lane & 15)];
            const int ve = etype[p0 + (lane & 15)];
            #pragma unroll
            for (int j = 0; j < 16; ++j) {
                const int src = __builtin_amdgcn_readfirstlane(__shfl(vi, j, 64));
                const int et  = __builtin_amdgcn_readfirstlane(__shfl(ve, j, 64));
                const float2 v = *(const float2*)&feat[src * K + d2];
                if      (et == 0) { acc[0].x += v.x; acc[0].y += v.y; }
                else if (et == 1) { acc[1].x += v.x; acc[1].y += v.y; }
                else if (et == 2) { acc[2].x += v.x; acc[2].y += v.y; }
                else if (et == 3) { acc[3].x += v.x; acc[3].y += v.y; }
                else if (et == 4) { acc[4].x += v.x; acc[4].y += v.y; }
                else if (et == 5) { acc[5].x += v.x; acc[5].y += v.y; }
                else if (et == 6) { acc[6].x += v.x; acc[6].y += v.y; }
                else              { acc[7].x += v.x; acc[7].y += v.y; }
            }
        } else {                          // generic fallback (never hit in bench)
            for (int e = p0; e < p0 + deg; ++e) {
                const int src = __builtin_amdgcn_readfirstlane(idx[e]);
                const int et  = __builtin_amdgcn_readfirstlane(etype[e]);
                const float2 v = *(const float2*)&feat[src * K + d2];
                if      (et == 0) { acc[0].x += v.x; acc[0].y += v.y; }
                else if (et == 1) { acc[1].x += v.x; acc[1].y += v.y; }
                else if (et == 2) { acc[2].x += v.x; acc[2].y += v.y; }
                else if (et == 3) { acc[3].x += v.x; acc[3].y += v.y; }
                else if (et == 4) { acc[4].x += v.x; acc[4].y += v.y; }
                else if (et == 5) { acc[5].x += v.x; acc[5].y += v.y; }
                else if (et == 6) { acc[6].x += v.x; acc[6].y += v.y; }
                else              { acc[7].x += v.x; acc[7].y += v.y; }
            }
        }
        #pragma unroll
        for (int r = 0; r < kR; ++r)
            *(float2*)&agg[n][r * K + d2] = acc[r];   // covers every slot: no zero-init needed
    }
}

// ---------------------------------------------------------------------------
// Layer 1: h1 = relu(bn( (sum_r agg_r @ W1[r]) / deg ))
// ---------------------------------------------------------------------------
__global__ __launch_bounds__(256, 2)
void rgcn_layer1(const float* __restrict__ x,
                 const float* __restrict__ W1,     // flat [1024][128]
                 const float* __restrict__ gamma,
                 const float* __restrict__ beta,
                 const float* __restrict__ mean,
                 const float* __restrict__ var,
                 const int*   __restrict__ ptr,
                 const int*   __restrict__ idx,
                 const int*   __restrict__ etype,
                 float*       __restrict__ h1)
{
    __shared__ float agg[kNT][kR * kIn];          // 64 KB
    const int tid  = threadIdx.x;
    const int base = blockIdx.x * kNT;

    phaseA<kIn>(x, ptr, idx, etype, base, agg);
    __syncthreads();

    // ---- Phase B: [16 x 1024] @ [1024 x 128] register-tiled ----------------
    const int h2 = tid & 63;                      // channel pair 2*h2, 2*h2+1
    const int ng = tid >> 6;                      // nodes ng*4 .. ng*4+3
    float acc[4][2];
    #pragma unroll
    for (int j = 0; j < 4; ++j) { acc[j][0] = 0.f; acc[j][1] = 0.f; }

    const int K = kR * kIn;                       // 1024
    for (int k0 = 0; k0 < K; k0 += 4) {
        const float4 a0 = *(const float4*)&agg[ng * 4 + 0][k0];
        const float4 a1 = *(const float4*)&agg[ng * 4 + 1][k0];
        const float4 a2 = *(const float4*)&agg[ng * 4 + 2][k0];
        const float4 a3 = *(const float4*)&agg[ng * 4 + 3][k0];
        #pragma unroll
        for (int j = 0; j < 4; ++j) {
            const float2 w = *(const float2*)&W1[(k0 + j) * kHid + h2 * 2];
            const float b0 = (&a0.x)[j], b1 = (&a1.x)[j];
            const float b2 = (&a2.x)[j], b3 = (&a3.x)[j];
            acc[0][0] += b0 * w.x;  acc[0][1] += b0 * w.y;
            acc[1][0] += b1 * w.x;  acc[1][1] += b1 * w.y;
            acc[2][0] += b2 * w.x;  acc[2][1] += b2 * w.y;
            acc[3][0] += b3 * w.x;  acc[3][1] += b3 * w.y;
        }
    }

    // ---- Epilogue: deg norm + BN (eval) + ReLU -----------------------------
    const int c0 = h2 * 2;
    const float is0 = rsqrtf(var[c0] + kBnEps);
    const float is1 = rsqrtf(var[c0 + 1] + kBnEps);
    const float g0 = gamma[c0] * is0,  g1 = gamma[c0 + 1] * is1;
    const float m0 = mean[c0],         m1 = mean[c0 + 1];
    const float bt0 = beta[c0],        bt1 = beta[c0 + 1];
    #pragma unroll
    for (int j = 0; j < 4; ++j) {
        const int node = base + ng * 4 + j;
        const float invdeg = 1.0f / (float)(ptr[node + 1] - ptr[node]);
        float v0 = (acc[j][0] * invdeg - m0) * g0 + bt0;
        float v1 = (acc[j][1] * invdeg - m1) * g1 + bt1;
        v0 = v0 > 0.f ? v0 : 0.f;
        v1 = v1 > 0.f ? v1 : 0.f;
        h1[node * kHid + c0]     = v0;
        h1[node * kHid + c0 + 1] = v1;
    }
}

// ---------------------------------------------------------------------------
// Layer 2: out = log_softmax( (sum_r agg_r @ W2[r]) / deg )
// ---------------------------------------------------------------------------
__global__ __launch_bounds__(256, 2)
void rgcn_layer2(const float* __restrict__ h1,
                 const float* __restrict__ W2,     // flat [1024][40]
                 const int*   __restrict__ ptr,
                 const int*   __restrict__ idx,
                 const int*   __restrict__ etype,
                 float*       __restrict__ out)
{
    __shared__ float agg[kNT][kR * kHid];         // 64 KB
    const int tid  = threadIdx.x;
    const int base = blockIdx.x * kNT;

    phaseA<kHid>(h1, ptr, idx, etype, base, agg);
    __syncthreads();

    // ---- Phase B: [16 x 1024] @ [1024 x 40] --------------------------------
    const int o  = tid & 63;                      // logit channel (active o<40)
    const int ng = tid >> 6;
    float acc[4] = {0.f, 0.f, 0.f, 0.f};

    const int K = kR * kHid;                      // 1024
    if (o < kOut) {
        for (int k0 = 0; k0 < K; k0 += 4) {
            const float4 a0 = *(const float4*)&agg[ng * 4 + 0][k0];
            const float4 a1 = *(const float4*)&agg[ng * 4 + 1][k0];
            const float4 a2 = *(const float4*)&agg[ng * 4 + 2][k0];
            const float4 a3 = *(const float4*)&agg[ng * 4 + 3][k0];
            #pragma unroll
            for (int j = 0; j < 4; ++j) {
                const float w = W2[(k0 + j) * kOut + o];
                acc[0] += (&a0.x)[j] * w;
                acc[1] += (&a1.x)[j] * w;
                acc[2] += (&a2.x)[j] * w;
                acc[3] += (&a3.x)[j] * w;
            }
        }
    }

    // ---- Epilogue: deg norm + log_softmax over 40 logits (wave reduce) -----
    #pragma unroll
    for (int j = 0; j < 4; ++j) {
        const int node = base + ng * 4 + j;
        const float invdeg = 1.0f / (float)(ptr[node + 1] - ptr[node]);
        const float v = (o < kOut) ? acc[j] * invdeg : -INFINITY;
        float m = v;
        #pragma unroll
        for (int off = 32; off > 0; off >>= 1)
            m = fmaxf(m, __shfl_xor(m, off, 64));
        float s = (o < kOut) ? expf(v - m) : 0.f;
        #pragma unroll
        for (int off = 32; off > 0; off >>= 1)
            s += __shfl_xor(s, off, 64);
        if (o < kOut)
            out[node * kOut + o] = v - m - logf(s);
    }
}

// ---------------------------------------------------------------------------
extern "C" void kernel_launch(void* const* d_in, const int* in_sizes, int n_in,
                              void* d_out, int out_size, void* d_ws, size_t ws_size,
                              hipStream_t stream)
{
    const float* x     = (const float*)d_in[0];
    const float* W1    = (const float*)d_in[1];
    const float* W2    = (const float*)d_in[2];
    const float* gamma = (const float*)d_in[3];
    const float* beta  = (const float*)d_in[4];
    const float* mean  = (const float*)d_in[5];
    const float* var   = (const float*)d_in[6];
    const int*   ptr   = (const int*)d_in[7];
    const int*   idx   = (const int*)d_in[8];
    const int*   et    = (const int*)d_in[9];
    float*       out   = (float*)d_out;
    float*       h1    = (float*)d_ws;            // [50000][128] f32 = 25.6 MB

    dim3 grid(kN / kNT), block(256);
    rgcn_layer1<<<grid, block, 0, stream>>>(x, W1, gamma, beta, mean, var,
                                            ptr, idx, et, h1);
    rgcn_layer2<<<grid, block, 0, stream>>>(h1, W2, ptr, idx, et, out);
}

// Round 3
// 542.500 us; speedup vs baseline: 2.9664x; 2.0333x over previous
//
#include <hip/hip_runtime.h>
#include <math.h>

typedef __attribute__((ext_vector_type(8))) short bf16x8;
typedef __attribute__((ext_vector_type(4))) float f32x4;

constexpr int kN   = 50000;
constexpr int kR   = 8;
constexpr int kIn  = 128;
constexpr int kHid = 128;
constexpr int kOut = 40;
constexpr int kNT  = 16;              // dst nodes per block
constexpr int kLds = 1032;            // ushort row stride: 1024 + 8 pad (16B-aligned rows)
constexpr float kBnEps = 1e-5f;

// bf16 helpers (RNE), bitwise to avoid header type friction
__device__ inline ushort f2bf(float x) {
    uint u = __float_as_uint(x);
    u += 0x7FFFu + ((u >> 16) & 1u);
    return (ushort)(u >> 16);
}
__device__ inline float bf2f(ushort s) { return __uint_as_float(((uint)s) << 16); }

// ---------------------------------------------------------------------------
// Pack W (fp32 [1024][N]) into MFMA B-fragment order, split hi/lo bf16.
// Fragment f = nt*32 + kt; lane L holds B[n = nt*16 + (L&15)][k = kt*32 + (L>>4)*8 + j].
// ---------------------------------------------------------------------------
__global__ void pack_w(const float* __restrict__ W, ushort* __restrict__ hi,
                       ushort* __restrict__ lo, int N)
{
    const int lane = threadIdx.x;                 // 64
    const int kt = blockIdx.x & 31;
    const int nt = blockIdx.x >> 5;
    const int n  = nt * 16 + (lane & 15);
    const int q  = lane >> 4;
    ushort hv[8], lv[8];
    #pragma unroll
    for (int j = 0; j < 8; ++j) {
        const int k = kt * 32 + q * 8 + j;
        const float w = (n < N) ? W[(size_t)k * N + n] : 0.f;
        const ushort h = f2bf(w);
        hv[j] = h;
        lv[j] = f2bf(w - bf2f(h));
    }
    const size_t o = ((size_t)blockIdx.x * 64 + lane) * 8;
    *(ushort4*)&hi[o]     = make_ushort4(hv[0], hv[1], hv[2], hv[3]);
    *(ushort4*)&hi[o + 4] = make_ushort4(hv[4], hv[5], hv[6], hv[7]);
    *(ushort4*)&lo[o]     = make_ushort4(lv[0], lv[1], lv[2], lv[3]);
    *(ushort4*)&lo[o + 4] = make_ushort4(lv[4], lv[5], lv[6], lv[7]);
}

// ---------------------------------------------------------------------------
// Phase A: per-relation neighbor sums, fp32 registers, then hi/lo bf16 to LDS.
// One wave per dst node; lane owns feature pair d = lane*2, lane*2+1.
// All 16 neighbor loads prefetched (single basic block) before branchy select.
// ---------------------------------------------------------------------------
template <bool BF16IN>
__device__ inline void phaseA(const void* __restrict__ featv,
                              const int* __restrict__ ptr,
                              const int* __restrict__ idx,
                              const int* __restrict__ etype,
                              int base,
                              ushort (*aggHi)[kLds], ushort (*aggLo)[kLds])
{
    const int tid  = threadIdx.x;
    const int lane = tid & 63;
    const int wid  = tid >> 6;
    const int d2   = lane * 2;

    for (int t = 0; t < kNT / 4; ++t) {
        const int n    = t * 4 + wid;
        const int node = base + n;
        const int p0   = ptr[node];
        const int deg  = ptr[node + 1] - p0;

        float2 acc[kR];
        #pragma unroll
        for (int r = 0; r < kR; ++r) acc[r] = make_float2(0.f, 0.f);

        if (deg == 16) {                          // fixed-degree fast path
            const int vi = idx[p0 + (lane & 15)];
            const int ve = etype[p0 + (lane & 15)];
            float2 v[16];
            #pragma unroll
            for (int j = 0; j < 16; ++j) {        // independent loads: one vmcnt wait
                const int src = __builtin_amdgcn_readlane(vi, j);
                if (BF16IN) {
                    const ushort2 u = *(const ushort2*)((const ushort*)featv + (size_t)src * kIn + d2);
                    v[j] = make_float2(bf2f(u.x), bf2f(u.y));
                } else {
                    v[j] = *(const float2*)((const float*)featv + (size_t)src * kIn + d2);
                }
            }
            #pragma unroll
            for (int j = 0; j < 16; ++j) {
                const int et = __builtin_amdgcn_readlane(ve, j);
                const float2 w = v[j];
                if      (et == 0) { acc[0].x += w.x; acc[0].y += w.y; }
                else if (et == 1) { acc[1].x += w.x; acc[1].y += w.y; }
                else if (et == 2) { acc[2].x += w.x; acc[2].y += w.y; }
                else if (et == 3) { acc[3].x += w.x; acc[3].y += w.y; }
                else if (et == 4) { acc[4].x += w.x; acc[4].y += w.y; }
                else if (et == 5) { acc[5].x += w.x; acc[5].y += w.y; }
                else if (et == 6) { acc[6].x += w.x; acc[6].y += w.y; }
                else              { acc[7].x += w.x; acc[7].y += w.y; }
            }
        } else {                                  // generic fallback
            for (int e = p0; e < p0 + deg; ++e) {
                const int src = __builtin_amdgcn_readfirstlane(idx[e]);
                const int et  = __builtin_amdgcn_readfirstlane(etype[e]);
                float2 w;
                if (BF16IN) {
                    const ushort2 u = *(const ushort2*)((const ushort*)featv + (size_t)src * kIn + d2);
                    w = make_float2(bf2f(u.x), bf2f(u.y));
                } else {
                    w = *(const float2*)((const float*)featv + (size_t)src * kIn + d2);
                }
                if      (et == 0) { acc[0].x += w.x; acc[0].y += w.y; }
                else if (et == 1) { acc[1].x += w.x; acc[1].y += w.y; }
                else if (et == 2) { acc[2].x += w.x; acc[2].y += w.y; }
                else if (et == 3) { acc[3].x += w.x; acc[3].y += w.y; }
                else if (et == 4) { acc[4].x += w.x; acc[4].y += w.y; }
                else if (et == 5) { acc[5].x += w.x; acc[5].y += w.y; }
                else if (et == 6) { acc[6].x += w.x; acc[6].y += w.y; }
                else              { acc[7].x += w.x; acc[7].y += w.y; }
            }
        }

        // hi/lo split to LDS: 2 consecutive bf16 per plane per r (4B stores,
        // dword addr = n*516 + r*64 + lane -> bank = lane%32, 2-way = free)
        #pragma unroll
        for (int r = 0; r < kR; ++r) {
            const ushort h0 = f2bf(acc[r].x);
            const ushort h1 = f2bf(acc[r].y);
            const ushort l0 = f2bf(acc[r].x - bf2f(h0));
            const ushort l1 = f2bf(acc[r].y - bf2f(h1));
            *(ushort2*)&aggHi[n][r * 128 + d2] = make_ushort2(h0, h1);
            *(ushort2*)&aggLo[n][r * 128 + d2] = make_ushort2(l0, l1);
        }
    }
}

// ---------------------------------------------------------------------------
// Layer 1: h1 = bf16( relu(bn( (sum_r agg_r @ W1[r]) / deg )) )
// Phase B: [16 x 1024] @ [1024 x 128] via 16x16x32 bf16 MFMA, 3-pass hi/lo.
// ---------------------------------------------------------------------------
__global__ __launch_bounds__(256, 2)
void rgcn_layer1(const float* __restrict__ x,
                 const ushort* __restrict__ W1hi, const ushort* __restrict__ W1lo,
                 const float* __restrict__ gamma, const float* __restrict__ beta,
                 const float* __restrict__ mean,  const float* __restrict__ var,
                 const int* __restrict__ ptr, const int* __restrict__ idx,
                 const int* __restrict__ etype,
                 ushort* __restrict__ h1b)
{
    __shared__ ushort aggHi[kNT][kLds];
    __shared__ ushort aggLo[kNT][kLds];
    const int tid  = threadIdx.x;
    const int base = blockIdx.x * kNT;

    phaseA<false>(x, ptr, idx, etype, base, aggHi, aggLo);
    __syncthreads();

    const int lane = tid & 63;
    const int wid  = tid >> 6;
    const int m    = lane & 15;                  // A row / D col
    const int q    = lane >> 4;
    const int nt0  = wid * 2, nt1 = nt0 + 1;     // wave owns 32 channels

    const bf16x8* Bh = (const bf16x8*)W1hi;
    const bf16x8* Bl = (const bf16x8*)W1lo;

    f32x4 acc0 = {0.f, 0.f, 0.f, 0.f};
    f32x4 acc1 = {0.f, 0.f, 0.f, 0.f};

    #pragma unroll 2
    for (int kt = 0; kt < 32; ++kt) {
        const bf16x8 ah  = *(const bf16x8*)&aggHi[m][kt * 32 + q * 8];
        const bf16x8 al  = *(const bf16x8*)&aggLo[m][kt * 32 + q * 8];
        const bf16x8 bh0 = Bh[((size_t)nt0 * 32 + kt) * 64 + lane];
        const bf16x8 bl0 = Bl[((size_t)nt0 * 32 + kt) * 64 + lane];
        const bf16x8 bh1 = Bh[((size_t)nt1 * 32 + kt) * 64 + lane];
        const bf16x8 bl1 = Bl[((size_t)nt1 * 32 + kt) * 64 + lane];
        acc0 = __builtin_amdgcn_mfma_f32_16x16x32_bf16(ah, bh0, acc0, 0, 0, 0);
        acc0 = __builtin_amdgcn_mfma_f32_16x16x32_bf16(al, bh0, acc0, 0, 0, 0);
        acc0 = __builtin_amdgcn_mfma_f32_16x16x32_bf16(ah, bl0, acc0, 0, 0, 0);
        acc1 = __builtin_amdgcn_mfma_f32_16x16x32_bf16(ah, bh1, acc1, 0, 0, 0);
        acc1 = __builtin_amdgcn_mfma_f32_16x16x32_bf16(al, bh1, acc1, 0, 0, 0);
        acc1 = __builtin_amdgcn_mfma_f32_16x16x32_bf16(ah, bl1, acc1, 0, 0, 0);
    }

    // Epilogue: deg norm + BN + ReLU, write bf16 h1
    const int cA = wid * 32 + m;                 // D col of acc0
    const int cB = cA + 16;                      // D col of acc1
    const float gA = gamma[cA] * rsqrtf(var[cA] + kBnEps);
    const float gB = gamma[cB] * rsqrtf(var[cB] + kBnEps);
    const float mA = mean[cA], mB = mean[cB];
    const float bA = beta[cA], bB = beta[cB];
    #pragma unroll
    for (int i = 0; i < 4; ++i) {
        const int node = base + q * 4 + i;       // D row
        const float invdeg = 1.0f / (float)(ptr[node + 1] - ptr[node]);
        float v0 = (acc0[i] * invdeg - mA) * gA + bA;
        float v1 = (acc1[i] * invdeg - mB) * gB + bB;
        v0 = fmaxf(v0, 0.f);
        v1 = fmaxf(v1, 0.f);
        h1b[(size_t)node * kHid + cA] = f2bf(v0);
        h1b[(size_t)node * kHid + cB] = f2bf(v1);
    }
}

// ---------------------------------------------------------------------------
// Layer 2: out = log_softmax( (sum_r agg_r @ W2[r]) / deg ), N padded 40->48
// ---------------------------------------------------------------------------
__global__ __launch_bounds__(256, 2)
void rgcn_layer2(const ushort* __restrict__ h1b,
                 const ushort* __restrict__ W2hi, const ushort* __restrict__ W2lo,
                 const int* __restrict__ ptr, const int* __restrict__ idx,
                 const int* __restrict__ etype,
                 float* __restrict__ out)
{
    __shared__ ushort aggHi[kNT][kLds];
    __shared__ ushort aggLo[kNT][kLds];
    __shared__ float logits[kNT][48];
    const int tid  = threadIdx.x;
    const int base = blockIdx.x * kNT;

    phaseA<true>(h1b, ptr, idx, etype, base, aggHi, aggLo);
    __syncthreads();

    const int lane = tid & 63;
    const int wid  = tid >> 6;
    const int m    = lane & 15;
    const int q    = lane >> 4;

    if (wid < 3) {                               // wave owns n-tile wid (16 cols)
        const bf16x8* Bh = (const bf16x8*)W2hi;
        const bf16x8* Bl = (const bf16x8*)W2lo;
        f32x4 acc = {0.f, 0.f, 0.f, 0.f};
        #pragma unroll 2
        for (int kt = 0; kt < 32; ++kt) {
            const bf16x8 ah = *(const bf16x8*)&aggHi[m][kt * 32 + q * 8];
            const bf16x8 al = *(const bf16x8*)&aggLo[m][kt * 32 + q * 8];
            const bf16x8 bh = Bh[((size_t)wid * 32 + kt) * 64 + lane];
            const bf16x8 bl = Bl[((size_t)wid * 32 + kt) * 64 + lane];
            acc = __builtin_amdgcn_mfma_f32_16x16x32_bf16(ah, bh, acc, 0, 0, 0);
            acc = __builtin_amdgcn_mfma_f32_16x16x32_bf16(al, bh, acc, 0, 0, 0);
            acc = __builtin_amdgcn_mfma_f32_16x16x32_bf16(ah, bl, acc, 0, 0, 0);
        }
        const int n = wid * 16 + m;              // logit column
        if (n < kOut) {
            #pragma unroll
            for (int i = 0; i < 4; ++i) {
                const int node = base + q * 4 + i;
                const float invdeg = 1.0f / (float)(ptr[node + 1] - ptr[node]);
                logits[q * 4 + i][n] = acc[i] * invdeg;
            }
        }
    }
    __syncthreads();

    // log_softmax: wave w handles nodes w*4 .. w*4+3
    #pragma unroll
    for (int i = 0; i < 4; ++i) {
        const int nrow = wid * 4 + i;
        const int node = base + nrow;
        const float v = (lane < kOut) ? logits[nrow][lane] : -INFINITY;
        float mx = v;
        #pragma unroll
        for (int off = 32; off > 0; off >>= 1)
            mx = fmaxf(mx, __shfl_xor(mx, off, 64));
        float s = (lane < kOut) ? __expf(v - mx) : 0.f;
        #pragma unroll
        for (int off = 32; off > 0; off >>= 1)
            s += __shfl_xor(s, off, 64);
        if (lane < kOut)
            out[(size_t)node * kOut + lane] = v - mx - __logf(s);
    }
}

// ---------------------------------------------------------------------------
extern "C" void kernel_launch(void* const* d_in, const int* in_sizes, int n_in,
                              void* d_out, int out_size, void* d_ws, size_t ws_size,
                              hipStream_t stream)
{
    const float* x     = (const float*)d_in[0];
    const float* W1    = (const float*)d_in[1];
    const float* W2    = (const float*)d_in[2];
    const float* gamma = (const float*)d_in[3];
    const float* beta  = (const float*)d_in[4];
    const float* mean  = (const float*)d_in[5];
    const float* var   = (const float*)d_in[6];
    const int*   ptr   = (const int*)d_in[7];
    const int*   idx   = (const int*)d_in[8];
    const int*   et    = (const int*)d_in[9];
    float*       out   = (float*)d_out;

    // Workspace layout (proven-safe budget: 25.6 MB used in R1)
    char* ws = (char*)d_ws;
    ushort* h1b  = (ushort*)ws;                              // 50000*128*2 = 12,800,000 B
    ushort* W1hi = (ushort*)(ws + 12800000);                 // 1024*128*2  =    262,144 B
    ushort* W1lo = (ushort*)(ws + 12800000 + 262144);
    ushort* W2hi = (ushort*)(ws + 12800000 + 524288);        // 1024*48*2   =     98,304 B
    ushort* W2lo = (ushort*)(ws + 12800000 + 524288 + 98304);

    pack_w<<<dim3(8 * 32), dim3(64), 0, stream>>>(W1, W1hi, W1lo, kHid);
    pack_w<<<dim3(3 * 32), dim3(64), 0, stream>>>(W2, W2hi, W2lo, kOut);

    dim3 grid(kN / kNT), block(256);
    rgcn_layer1<<<grid, block, 0, stream>>>(x, W1hi, W1lo, gamma, beta, mean, var,
                                            ptr, idx, et, h1b);
    rgcn_layer2<<<grid, block, 0, stream>>>(h1b, W2hi, W2lo, ptr, idx, et, out);
}